// Round 4
// baseline (550.097 us; speedup 1.0000x reference)
//
#include <hip/hip_runtime.h>
#include <hip/hip_bf16.h>
#include <stdint.h>

#define BDIM 4
#define SDIM 1024
#define DDIM 1024
#define HDIM 16
#define DHDIM 64

typedef __bf16 bf16_t;
typedef __bf16 bf16x8 __attribute__((ext_vector_type(8)));
typedef __bf16 bf16x4 __attribute__((ext_vector_type(4)));
typedef float f32x4 __attribute__((ext_vector_type(4)));

typedef __attribute__((address_space(3))) uint32_t lds_u32;
typedef const __attribute__((address_space(1))) uint32_t glb_u32;

__device__ __forceinline__ void glds16(const void* g, void* l) {
    __builtin_amdgcn_global_load_lds((glb_u32*)g, (lds_u32*)l, 16, 0, 0);
}

// ---------------- conversions ----------------

__global__ __launch_bounds__(256) void convert_x_kernel(const float* __restrict__ X,
                                                        bf16_t* __restrict__ Xb, int n) {
    int i = (blockIdx.x * 256 + threadIdx.x) * 4;
    if (i >= n) return;
    float4 v = *(const float4*)(X + i);
    bf16x4 o;
    o[0] = (bf16_t)v.x; o[1] = (bf16_t)v.y; o[2] = (bf16_t)v.z; o[3] = (bf16_t)v.w;
    *(bf16x4*)(Xb + i) = o;
}

// W[k][n] fp32 -> Wt[n][k] bf16, for 4 weights (z selects)
__global__ __launch_bounds__(256) void transpose_w_kernel(const float* __restrict__ W0,
                                                          const float* __restrict__ W1,
                                                          const float* __restrict__ W2,
                                                          const float* __restrict__ W3,
                                                          bf16_t* __restrict__ Wt) {
    __shared__ float tile[32][33];
    int z = blockIdx.z;
    const float* W = (z == 0) ? W0 : (z == 1) ? W1 : (z == 2) ? W2 : W3;
    bf16_t* dst = Wt + (size_t)z * DDIM * DDIM;
    int bx = blockIdx.x * 32;  // n tile
    int by = blockIdx.y * 32;  // k tile
    int x = threadIdx.x & 31, y0 = threadIdx.x >> 5;
#pragma unroll
    for (int i = 0; i < 4; i++) {
        int y = y0 + i * 8;
        tile[y][x] = W[(size_t)(by + y) * DDIM + bx + x];
    }
    __syncthreads();
#pragma unroll
    for (int i = 0; i < 4; i++) {
        int y = y0 + i * 8;
        dst[(size_t)(bx + y) * DDIM + by + x] = (bf16_t)tile[x][y];
    }
}

// Detect mask element layout: uint8 bools -> bytes at i%4!=0 nonzero somewhere;
// int32 -> those bytes all 0. flag=1 means stride 1 (uint8), else stride 4.
__global__ __launch_bounds__(1024) void mask_flag_kernel(const unsigned char* __restrict__ mb,
                                                         int* __restrict__ flag) {
    __shared__ int any;
    if (threadIdx.x == 0) any = 0;
    __syncthreads();
    int loc = 0;
    for (int i = threadIdx.x; i < BDIM * SDIM; i += 1024)
        if ((i & 3) && mb[i]) loc = 1;
    if (loc) any = 1;
    __syncthreads();
    if (threadIdx.x == 0) *flag = any ? 1 : 0;
}

// ---------------- GEMM: C[m,n] = sum_k A[m,k] * Bt[n,k] (m97-style) ----------------
template <int MODE>
__global__ __launch_bounds__(256) void gemm_bt_kernel(const bf16_t* __restrict__ A,
                                                      const bf16_t* __restrict__ Bt,
                                                      bf16_t* __restrict__ Qo, bf16_t* __restrict__ Ko,
                                                      bf16_t* __restrict__ Vto, float* __restrict__ Co) {
    __shared__ bf16_t As[128 * 32];
    __shared__ bf16_t Bs[128 * 32];
    const int m0 = blockIdx.x * 128;
    const int n0 = blockIdx.y * 128;
    const int t = threadIdx.x;
    const int lane = t & 63, w = t >> 6;
    const int wm = w & 1, wn = w >> 1;
    const int low = lane & 15, quad = lane >> 4;
    f32x4 acc[4][4] = {};

    const int srow = w * 16 + (lane >> 2);
    const int koff = (lane & 3) * 8;
    const bf16_t* Ag = A + (size_t)(m0 + srow) * DDIM + koff;
    const bf16_t* Bg = Bt + (size_t)(n0 + srow) * DDIM + koff;
    bf16_t* AsW = As + w * 512;
    bf16_t* BsW = Bs + w * 512;

    for (int k0 = 0; k0 < DDIM; k0 += 32) {
        __syncthreads();
        glds16(Ag + k0, AsW);
        glds16(Ag + (size_t)64 * DDIM + k0, AsW + 64 * 32);
        glds16(Bg + k0, BsW);
        glds16(Bg + (size_t)64 * DDIM + k0, BsW + 64 * 32);
        __syncthreads();
        bf16x8 af[4], bv[4];
#pragma unroll
        for (int mt = 0; mt < 4; mt++)
            af[mt] = *(const bf16x8*)(As + (wm * 64 + mt * 16 + low) * 32 + quad * 8);
#pragma unroll
        for (int nt = 0; nt < 4; nt++)
            bv[nt] = *(const bf16x8*)(Bs + (wn * 64 + nt * 16 + low) * 32 + quad * 8);
#pragma unroll
        for (int mt = 0; mt < 4; mt++)
#pragma unroll
            for (int nt = 0; nt < 4; nt++)
                acc[mt][nt] = __builtin_amdgcn_mfma_f32_16x16x32_bf16(af[mt], bv[nt], acc[mt][nt], 0, 0, 0);
    }

#pragma unroll
    for (int mt = 0; mt < 4; mt++) {
        const int mbase = m0 + wm * 64 + mt * 16 + quad * 4;
#pragma unroll
        for (int nt = 0; nt < 4; nt++) {
            const int ncol = n0 + wn * 64 + nt * 16 + low;
            if (MODE == 0) {
                const int which = ncol >> 10, nl = ncol & 1023;
                const int hh = nl >> 6, dh = nl & 63;
                const int bb = mbase >> 10, s = mbase & 1023;
                if (which == 2) {
                    bf16x4 pv;
#pragma unroll
                    for (int r = 0; r < 4; r++) pv[r] = (bf16_t)acc[mt][nt][r];
                    *(bf16x4*)(Vto + ((size_t)((bb * HDIM + hh) * DHDIM + dh)) * SDIM + s) = pv;
                } else if (which == 0) {
#pragma unroll
                    for (int r = 0; r < 4; r++)
                        Qo[((size_t)(bb * HDIM + hh) * SDIM + (s + r)) * DHDIM + dh] =
                            (bf16_t)(acc[mt][nt][r] * 0.125f);
                } else {
#pragma unroll
                    for (int r = 0; r < 4; r++)
                        Ko[((size_t)(bb * HDIM + hh) * SDIM + (s + r)) * DHDIM + dh] =
                            (bf16_t)acc[mt][nt][r];
                }
            } else {
#pragma unroll
                for (int r = 0; r < 4; r++)
                    Co[(size_t)(mbase + r) * DDIM + ncol] = acc[mt][nt][r];
            }
        }
    }
}

// ---------------- fused attention ----------------
// 512 blocks x 512 threads (8 waves). xcd = bid&7 -> (b = xcd>>1, hh = xcd&1):
// each XCD's 64 blocks share ONE 2 MB K/V slice (L2-resident, re-read by all).
// qt = bid>>3 -> q0 = qt*16; wave w = head hh*8+w, one 16-row q tile.
// 2 blocks/CU (LDS 31 KB, VGPR<=128): 16 waves/CU in TWO independent barrier
// domains -> mutual latency hiding (R2's 1-block/CU was the bottleneck).
// Swapped QK^T (mfma(K,Q)): lane owns q=low, k=quad*4+r(+16nt); softmax is
// balanced trees + 2 shfl_xor; T13 defer-max skips rescale when max drift <= 8.
// Bias fp32->bf16 LDS [h8][q16][k40], mask folded, double-buffered, prefetched
// one chunk ahead in registers (2 float4/thread).
__global__ __launch_bounds__(512, 4) void attn_kernel(const bf16_t* __restrict__ Q,
                                                      const bf16_t* __restrict__ K,
                                                      const bf16_t* __restrict__ Vt,
                                                      const float* __restrict__ inter,
                                                      const unsigned char* __restrict__ maskb,
                                                      const int* __restrict__ flagp,
                                                      bf16_t* __restrict__ hid) {
    constexpr int KS = 40;            // k stride (32 k + 8 pad) bf16
    constexpr int HS = 16 * KS + 8;   // per-h stride = 648 bf16
    __shared__ bf16_t bias_l[2][8 * HS];  // 2 x 10368 B
    __shared__ bf16_t P[8][16 * KS];      // 10.25 KB
    const int bid = blockIdx.x;
    const int xcd = bid & 7;
    const int b = xcd >> 1, hh = xcd & 1;
    const int q0 = (bid >> 3) * 16;
    const int t = threadIdx.x;
    const int w = t >> 6, lane = t & 63;
    const int low = lane & 15, quad = lane >> 4;
    const int h = hh * 8 + w;
    const int mstride = (*flagp) ? 1 : 4;

    // staging: wave w stages q-rows {w, w+8}; lane -> (k = lane>>1, hp = lane&1)
    const int sk = lane >> 1, shp = lane & 1;
    const float* srcB = inter + ((size_t)(b * SDIM + q0) * SDIM + sk) * HDIM + hh * 8 + shp * 4;
    const unsigned char* mb = maskb + (size_t)b * SDIM * mstride;
    constexpr size_t ROWSTRIDE = (size_t)SDIM * HDIM;  // floats per +1 q row

    // Q fragments (B-operand; col q = q0+low) for head h
    const bf16_t* Qb = Q + ((size_t)(b * HDIM + h) * SDIM + q0) * DHDIM;
    bf16x8 qf0 = *(const bf16x8*)(Qb + low * DHDIM + quad * 8);
    bf16x8 qf1 = *(const bf16x8*)(Qb + low * DHDIM + 32 + quad * 8);

    const bf16_t* Kb = K + (size_t)(b * HDIM + h) * SDIM * DHDIM;
    const bf16_t* VtB = Vt + (size_t)(b * HDIM + h) * DHDIM * SDIM;
    bf16_t* Pw = &P[w][0];

    float mrow = -3.0e38f, lrow = 0.f;
    f32x4 accO[4] = {};

    // ---- prologue: stage bias chunk 0 into buf 0 ----
    {
        float4 v0 = *(const float4*)(srcB + (size_t)w * ROWSTRIDE);
        float4 v1 = *(const float4*)(srcB + (size_t)(w + 8) * ROWSTRIDE);
        float pen = mb[sk * mstride] ? 0.f : 1.0e9f;
        bf16_t* d0 = &bias_l[0][(shp * 4) * HS + w * KS + sk];
        bf16_t* d1 = &bias_l[0][(shp * 4) * HS + (w + 8) * KS + sk];
        d0[0 * HS] = (bf16_t)(v0.x - pen); d0[1 * HS] = (bf16_t)(v0.y - pen);
        d0[2 * HS] = (bf16_t)(v0.z - pen); d0[3 * HS] = (bf16_t)(v0.w - pen);
        d1[0 * HS] = (bf16_t)(v1.x - pen); d1[1 * HS] = (bf16_t)(v1.y - pen);
        d1[2 * HS] = (bf16_t)(v1.z - pen); d1[3 * HS] = (bf16_t)(v1.w - pen);
    }

    for (int c = 0; c < SDIM / 32; c++) {
        __syncthreads();  // buf[c&1] ready; prior readers of buf[(c+1)&1] done
        const int kbase = c * 32;

        // ---- K fragments first (QK^T depends on them) ----
        const bf16_t* kpA = Kb + (size_t)(kbase + low) * DHDIM;
        const bf16_t* kpB = Kb + (size_t)(kbase + 16 + low) * DHDIM;
        bf16x8 kA0 = *(const bf16x8*)(kpA + quad * 8);
        bf16x8 kA1 = *(const bf16x8*)(kpA + 32 + quad * 8);
        bf16x8 kB0 = *(const bf16x8*)(kpB + quad * 8);
        bf16x8 kB1 = *(const bf16x8*)(kpB + 32 + quad * 8);

        // ---- V^T fragments (consumed at PV) ----
        bf16x8 vf[4];
#pragma unroll
        for (int nt = 0; nt < 4; nt++)
            vf[nt] = *(const bf16x8*)(VtB + (size_t)(nt * 16 + low) * SDIM + kbase + quad * 8);

        // ---- next-chunk bias + mask prefetch (lands during compute) ----
        float4 nv0, nv1; float npen = 0.f;
        if (c < SDIM / 32 - 1) {
            const float* s2 = srcB + (size_t)(c + 1) * 32 * HDIM;
            nv0 = *(const float4*)(s2 + (size_t)w * ROWSTRIDE);
            nv1 = *(const float4*)(s2 + (size_t)(w + 8) * ROWSTRIDE);
            npen = mb[((c + 1) * 32 + sk) * mstride] ? 0.f : 1.0e9f;
        }

        // ---- S^T = K Q^T (row=k, col=q) ----
        f32x4 s0 = {}, s1 = {};
        s0 = __builtin_amdgcn_mfma_f32_16x16x32_bf16(kA0, qf0, s0, 0, 0, 0);
        s0 = __builtin_amdgcn_mfma_f32_16x16x32_bf16(kA1, qf1, s0, 0, 0, 0);
        s1 = __builtin_amdgcn_mfma_f32_16x16x32_bf16(kB0, qf0, s1, 0, 0, 0);
        s1 = __builtin_amdgcn_mfma_f32_16x16x32_bf16(kB1, qf1, s1, 0, 0, 0);

        // ---- + bias (mask folded): lane q = low, k = nt*16 + quad*4 + r ----
        const bf16_t* bc = &bias_l[c & 1][w * HS + low * KS];
        bf16x4 bv0 = *(const bf16x4*)(bc + quad * 4);
        bf16x4 bv1 = *(const bf16x4*)(bc + 16 + quad * 4);
        float sv[8];
#pragma unroll
        for (int r = 0; r < 4; r++) {
            sv[r] = s0[r] + (float)bv0[r];
            sv[4 + r] = s1[r] + (float)bv1[r];
        }

        // ---- online softmax, balanced trees; T13 defer-max ----
        float vmx = fmaxf(fmaxf(fmaxf(sv[0], sv[1]), fmaxf(sv[2], sv[3])),
                          fmaxf(fmaxf(sv[4], sv[5]), fmaxf(sv[6], sv[7])));
        vmx = fmaxf(vmx, __shfl_xor(vmx, 16));
        vmx = fmaxf(vmx, __shfl_xor(vmx, 32));
        if (__any(vmx > mrow + 8.f)) {
            float mn = fmaxf(mrow, vmx);
            float alpha = __expf(mrow - mn);
            mrow = mn;
            lrow *= alpha;
#pragma unroll
            for (int r = 0; r < 4; r++) {
                float ar = __shfl(alpha, (lane & 48) | (quad * 4 + r));
#pragma unroll
                for (int nt = 0; nt < 4; nt++) accO[nt][r] *= ar;
            }
        }
        float e[8];
#pragma unroll
        for (int j = 0; j < 8; j++) e[j] = __expf(sv[j] - mrow);
        bf16x4 p0, p1;
#pragma unroll
        for (int j = 0; j < 4; j++) { p0[j] = (bf16_t)e[j]; p1[j] = (bf16_t)e[4 + j]; }
        float ps = ((e[0] + e[1]) + (e[2] + e[3])) + ((e[4] + e[5]) + (e[6] + e[7]));
        ps += __shfl_xor(ps, 16);
        ps += __shfl_xor(ps, 32);
        lrow += ps;

        // ---- P -> wave-private LDS (A layout rows q=low), no barrier ----
        *(bf16x4*)(Pw + low * KS + quad * 4) = p0;
        *(bf16x4*)(Pw + low * KS + 16 + quad * 4) = p1;
        bf16x8 pf = *(const bf16x8*)(Pw + low * KS + quad * 8);

        // ---- O += P V ----
#pragma unroll
        for (int nt = 0; nt < 4; nt++)
            accO[nt] = __builtin_amdgcn_mfma_f32_16x16x32_bf16(pf, vf[nt], accO[nt], 0, 0, 0);

        // ---- stage chunk c+1 into the other buffer ----
        if (c < SDIM / 32 - 1) {
            bf16_t* d0 = &bias_l[(c + 1) & 1][(shp * 4) * HS + w * KS + sk];
            bf16_t* d1 = &bias_l[(c + 1) & 1][(shp * 4) * HS + (w + 8) * KS + sk];
            d0[0 * HS] = (bf16_t)(nv0.x - npen); d0[1 * HS] = (bf16_t)(nv0.y - npen);
            d0[2 * HS] = (bf16_t)(nv0.z - npen); d0[3 * HS] = (bf16_t)(nv0.w - npen);
            d1[0 * HS] = (bf16_t)(nv1.x - npen); d1[1 * HS] = (bf16_t)(nv1.y - npen);
            d1[2 * HS] = (bf16_t)(nv1.z - npen); d1[3 * HS] = (bf16_t)(nv1.w - npen);
        }
    }

    // ---- epilogue: hidden[b, q, h*64+dh] bf16 ----
    float linv = 1.f / lrow;
#pragma unroll
    for (int r = 0; r < 4; r++) {
        float lr = __shfl(linv, (lane & 48) | (quad * 4 + r));
#pragma unroll
        for (int nt = 0; nt < 4; nt++) {
            hid[((size_t)b * SDIM + q0 + quad * 4 + r) * DDIM + h * 64 + nt * 16 + low] =
                (bf16_t)(accO[nt][r] * lr);
        }
    }
}

// ---------------- launcher ----------------

extern "C" void kernel_launch(void* const* d_in, const int* in_sizes, int n_in,
                              void* d_out, int out_size, void* d_ws, size_t ws_size,
                              hipStream_t stream) {
    const float* X = (const float*)d_in[0];
    const unsigned char* maskb = (const unsigned char*)d_in[1];
    const float* inter = (const float*)d_in[2];
    const float* WQ = (const float*)d_in[3];
    const float* WK = (const float*)d_in[4];
    const float* WV = (const float*)d_in[5];
    const float* WO = (const float*)d_in[6];
    float* out = (float*)d_out;

    char* ws = (char*)d_ws;
    const size_t MB = 1024 * 1024;
    bf16_t* Xb  = (bf16_t*)(ws + 0 * MB);
    bf16_t* Wt  = (bf16_t*)(ws + 8 * MB);    // [4][1024][1024] bf16 transposed
    bf16_t* Qm  = (bf16_t*)(ws + 16 * MB);   // [B,H,S,DH]
    bf16_t* Km  = (bf16_t*)(ws + 24 * MB);   // [B,H,S,DH]
    bf16_t* Vtm = (bf16_t*)(ws + 32 * MB);   // [B,H,DH,S]  (transposed V)
    bf16_t* hid = (bf16_t*)(ws + 40 * MB);   // [B,S,D] bf16
    int* flag   = (int*)(ws + 48 * MB);

    convert_x_kernel<<<BDIM * SDIM * DDIM / (256 * 4), 256, 0, stream>>>(X, Xb, BDIM * SDIM * DDIM);
    transpose_w_kernel<<<dim3(32, 32, 4), 256, 0, stream>>>(WQ, WK, WV, WO, Wt);
    mask_flag_kernel<<<1, 1024, 0, stream>>>(maskb, flag);
    gemm_bt_kernel<0><<<dim3(32, 24), 256, 0, stream>>>(Xb, Wt, Qm, Km, Vtm, nullptr);
    attn_kernel<<<dim3(512), 512, 0, stream>>>(Qm, Km, Vtm, inter, maskb, flag, hid);
    gemm_bt_kernel<1><<<dim3(32, 8), 256, 0, stream>>>(hid, Wt + (size_t)3 * DDIM * DDIM,
                                                       nullptr, nullptr, nullptr, out);
}

// Round 5
// 536.685 us; speedup vs baseline: 1.0250x; 1.0250x over previous
//
#include <hip/hip_runtime.h>
#include <hip/hip_bf16.h>
#include <stdint.h>

#define BDIM 4
#define SDIM 1024
#define DDIM 1024
#define HDIM 16
#define DHDIM 64

typedef __bf16 bf16_t;
typedef __bf16 bf16x8 __attribute__((ext_vector_type(8)));
typedef __bf16 bf16x4 __attribute__((ext_vector_type(4)));
typedef float f32x4 __attribute__((ext_vector_type(4)));

typedef __attribute__((address_space(3))) uint32_t lds_u32;
typedef const __attribute__((address_space(1))) uint32_t glb_u32;

__device__ __forceinline__ void glds16(const void* g, void* l) {
    __builtin_amdgcn_global_load_lds((glb_u32*)g, (lds_u32*)l, 16, 0, 0);
}

// ---------------- conversions ----------------

__global__ __launch_bounds__(256) void convert_x_kernel(const float* __restrict__ X,
                                                        bf16_t* __restrict__ Xb, int n) {
    int i = (blockIdx.x * 256 + threadIdx.x) * 4;
    if (i >= n) return;
    float4 v = *(const float4*)(X + i);
    bf16x4 o;
    o[0] = (bf16_t)v.x; o[1] = (bf16_t)v.y; o[2] = (bf16_t)v.z; o[3] = (bf16_t)v.w;
    *(bf16x4*)(Xb + i) = o;
}

// W[k][n] fp32 -> Wt[n][k] bf16, for 4 weights (z selects)
__global__ __launch_bounds__(256) void transpose_w_kernel(const float* __restrict__ W0,
                                                          const float* __restrict__ W1,
                                                          const float* __restrict__ W2,
                                                          const float* __restrict__ W3,
                                                          bf16_t* __restrict__ Wt) {
    __shared__ float tile[32][33];
    int z = blockIdx.z;
    const float* W = (z == 0) ? W0 : (z == 1) ? W1 : (z == 2) ? W2 : W3;
    bf16_t* dst = Wt + (size_t)z * DDIM * DDIM;
    int bx = blockIdx.x * 32;  // n tile
    int by = blockIdx.y * 32;  // k tile
    int x = threadIdx.x & 31, y0 = threadIdx.x >> 5;
#pragma unroll
    for (int i = 0; i < 4; i++) {
        int y = y0 + i * 8;
        tile[y][x] = W[(size_t)(by + y) * DDIM + bx + x];
    }
    __syncthreads();
#pragma unroll
    for (int i = 0; i < 4; i++) {
        int y = y0 + i * 8;
        dst[(size_t)(bx + y) * DDIM + by + x] = (bf16_t)tile[x][y];
    }
}

// Detect mask element layout: uint8 bools -> bytes at i%4!=0 nonzero somewhere;
// int32 -> those bytes all 0. flag=1 means stride 1 (uint8), else stride 4.
__global__ __launch_bounds__(1024) void mask_flag_kernel(const unsigned char* __restrict__ mb,
                                                         int* __restrict__ flag) {
    __shared__ int any;
    if (threadIdx.x == 0) any = 0;
    __syncthreads();
    int loc = 0;
    for (int i = threadIdx.x; i < BDIM * SDIM; i += 1024)
        if ((i & 3) && mb[i]) loc = 1;
    if (loc) any = 1;
    __syncthreads();
    if (threadIdx.x == 0) *flag = any ? 1 : 0;
}

// ---------------- bias transpose: inter[b][q][k][h] fp32 -> biasT[b][h][q][k] bf16,
// mask penalty folded (stored value = inter - (mask ? 0 : 1e9)). ----------------
// block = (b, 8 q rows, 128 k); LDS tile [16h][8q][136k] bf16 (pad 8 kills conflicts)
__global__ __launch_bounds__(256) void transpose_bias_kernel(const float* __restrict__ inter,
                                                             const unsigned char* __restrict__ maskb,
                                                             const int* __restrict__ flagp,
                                                             bf16_t* __restrict__ biasT) {
    __shared__ bf16_t tile[16 * 8 * 136];  // 34816 B
    const int k0 = blockIdx.x * 128, q0 = blockIdx.y * 8, b = blockIdx.z;
    const int tid = threadIdx.x;
    const int mstride = (*flagp) ? 1 : 4;
    const unsigned char* mb = maskb + (size_t)b * SDIM * mstride;
    const float* src = inter + ((size_t)(b * SDIM + q0) * SDIM + k0) * HDIM;
#pragma unroll
    for (int it = 0; it < 16; it++) {
        int j = it * 256 + tid;
        int h4 = j & 3, k = (j >> 2) & 127, q = j >> 9;
        float4 v = *(const float4*)(src + ((size_t)q * SDIM + k) * HDIM + h4 * 4);
        float pen = mb[(k0 + k) * mstride] ? 0.f : 1.0e9f;
        bf16_t* d = &tile[(h4 * 4) * 1088 + q * 136 + k];
        d[0 * 1088] = (bf16_t)(v.x - pen);
        d[1 * 1088] = (bf16_t)(v.y - pen);
        d[2 * 1088] = (bf16_t)(v.z - pen);
        d[3 * 1088] = (bf16_t)(v.w - pen);
    }
    __syncthreads();
#pragma unroll
    for (int rep = 0; rep < 2; rep++) {
        int u = rep * 256 + tid;
        int h = u >> 5, q = (u >> 2) & 7, kp = u & 3;
        const bf16_t* s = &tile[h * 1088 + q * 136 + kp * 32];
        bf16_t* d = biasT + ((size_t)(b * HDIM + h) * SDIM + (q0 + q)) * SDIM + k0 + kp * 32;
#pragma unroll
        for (int ss = 0; ss < 4; ss++)
            *(bf16x8*)(d + ss * 8) = *(const bf16x8*)(s + ss * 8);
    }
}

// ---------------- GEMM: C[m,n] = sum_k A[m,k] * Bt[n,k] (m97-style) ----------------
template <int MODE>
__global__ __launch_bounds__(256) void gemm_bt_kernel(const bf16_t* __restrict__ A,
                                                      const bf16_t* __restrict__ Bt,
                                                      bf16_t* __restrict__ Qo, bf16_t* __restrict__ Ko,
                                                      bf16_t* __restrict__ Vto, float* __restrict__ Co) {
    __shared__ bf16_t As[128 * 32];
    __shared__ bf16_t Bs[128 * 32];
    const int m0 = blockIdx.x * 128;
    const int n0 = blockIdx.y * 128;
    const int t = threadIdx.x;
    const int lane = t & 63, w = t >> 6;
    const int wm = w & 1, wn = w >> 1;
    const int low = lane & 15, quad = lane >> 4;
    f32x4 acc[4][4] = {};

    const int srow = w * 16 + (lane >> 2);
    const int koff = (lane & 3) * 8;
    const bf16_t* Ag = A + (size_t)(m0 + srow) * DDIM + koff;
    const bf16_t* Bg = Bt + (size_t)(n0 + srow) * DDIM + koff;
    bf16_t* AsW = As + w * 512;
    bf16_t* BsW = Bs + w * 512;

    for (int k0 = 0; k0 < DDIM; k0 += 32) {
        __syncthreads();
        glds16(Ag + k0, AsW);
        glds16(Ag + (size_t)64 * DDIM + k0, AsW + 64 * 32);
        glds16(Bg + k0, BsW);
        glds16(Bg + (size_t)64 * DDIM + k0, BsW + 64 * 32);
        __syncthreads();
        bf16x8 af[4], bv[4];
#pragma unroll
        for (int mt = 0; mt < 4; mt++)
            af[mt] = *(const bf16x8*)(As + (wm * 64 + mt * 16 + low) * 32 + quad * 8);
#pragma unroll
        for (int nt = 0; nt < 4; nt++)
            bv[nt] = *(const bf16x8*)(Bs + (wn * 64 + nt * 16 + low) * 32 + quad * 8);
#pragma unroll
        for (int mt = 0; mt < 4; mt++)
#pragma unroll
            for (int nt = 0; nt < 4; nt++)
                acc[mt][nt] = __builtin_amdgcn_mfma_f32_16x16x32_bf16(af[mt], bv[nt], acc[mt][nt], 0, 0, 0);
    }

#pragma unroll
    for (int mt = 0; mt < 4; mt++) {
        const int mbase = m0 + wm * 64 + mt * 16 + quad * 4;
#pragma unroll
        for (int nt = 0; nt < 4; nt++) {
            const int ncol = n0 + wn * 64 + nt * 16 + low;
            if (MODE == 0) {
                const int which = ncol >> 10, nl = ncol & 1023;
                const int hh = nl >> 6, dh = nl & 63;
                const int bb = mbase >> 10, s = mbase & 1023;
                if (which == 2) {
                    bf16x4 pv;
#pragma unroll
                    for (int r = 0; r < 4; r++) pv[r] = (bf16_t)acc[mt][nt][r];
                    *(bf16x4*)(Vto + ((size_t)((bb * HDIM + hh) * DHDIM + dh)) * SDIM + s) = pv;
                } else if (which == 0) {
#pragma unroll
                    for (int r = 0; r < 4; r++)
                        Qo[((size_t)(bb * HDIM + hh) * SDIM + (s + r)) * DHDIM + dh] =
                            (bf16_t)(acc[mt][nt][r] * 0.125f);
                } else {
#pragma unroll
                    for (int r = 0; r < 4; r++)
                        Ko[((size_t)(bb * HDIM + hh) * SDIM + (s + r)) * DHDIM + dh] =
                            (bf16_t)acc[mt][nt][r];
                }
            } else {
#pragma unroll
                for (int r = 0; r < 4; r++)
                    Co[(size_t)(mbase + r) * DDIM + ncol] = acc[mt][nt][r];
            }
        }
    }
}

// ---------------- fused attention ----------------
// 512 blocks x 512 threads (8 waves). Block = ONE (b, h) and a 128-q group:
// b = bid&3, h = (bid>>2)&15, qg = bid>>6 -> q0 = qg*128. Wave w owns q rows
// [q0+w*16, +16). K/V chunk (32 keys) staged ONCE per block into LDS via
// global_load_lds (waves 0-3: K 1KB each; waves 4-7: V^T 1KB each), shared by
// all 8 waves -> K/V global traffic 131 MB total (8x less than per-wave reads).
// XOR-swizzled SOURCE addresses (linear LDS dest) so ds_read_b128 frag reads
// are conflict-free: K[row][u] holds global unit u^(row&7); V[dh][u] holds
// global ksub u^(dh&3). Bias comes from pre-transposed bf16 biasT[b][h][q][k]
// (mask folded), k-contiguous b64 loads register-prefetched one chunk ahead.
// Swapped QK^T (mfma(K,Q)): lane owns q=low; balanced-tree softmax + 2
// shfl_xor; T13 defer-max. One barrier per chunk (dbuf K/V).
__global__ __launch_bounds__(512, 4) void attn_kernel(const bf16_t* __restrict__ Q,
                                                      const bf16_t* __restrict__ K,
                                                      const bf16_t* __restrict__ Vt,
                                                      const bf16_t* __restrict__ biasT,
                                                      bf16_t* __restrict__ hid) {
    __shared__ bf16_t Ks[2][2048];   // [buf][row32][u8*8] swizzled, 4 KB/buf
    __shared__ bf16_t Vs[2][2048];   // [buf][dh64][u4*8] swizzled, 4 KB/buf
    __shared__ bf16_t P[8][16 * 40]; // per-wave P tiles, 10 KB
    const int bid = blockIdx.x;
    const int b = bid & 3, h = (bid >> 2) & 15, qg = bid >> 6;
    const int q0 = qg * 128;
    const int t = threadIdx.x;
    const int w = t >> 6, lane = t & 63;
    const int low = lane & 15, quad = lane >> 4;
    const int qw = q0 + w * 16;  // wave's q-subtile base

    // Q fragments (B-operand; col q = qw+low)
    const bf16_t* Qb = Q + ((size_t)(b * HDIM + h) * SDIM + qw) * DHDIM;
    bf16x8 qf0 = *(const bf16x8*)(Qb + low * DHDIM + quad * 8);
    bf16x8 qf1 = *(const bf16x8*)(Qb + low * DHDIM + 32 + quad * 8);

    const bf16_t* Kb = K + (size_t)(b * HDIM + h) * SDIM * DHDIM;
    const bf16_t* VtB = Vt + (size_t)(b * HDIM + h) * DHDIM * SDIM;
    // per-lane bias row (q = qw+low), k contiguous
    const bf16_t* Bq = biasT + ((size_t)(b * HDIM + h) * SDIM + qw + low) * SDIM;
    bf16_t* Pw = &P[w][0];

    // staging source (per-lane, pre-swizzled) and LDS dest (linear, wave-uniform)
    const bf16_t* stg_src;
    size_t kmul;
    bf16_t* stg_base;
    if (w < 4) {  // K rows w*8 + rl; unit stored u holds global unit u^rl
        int rl = lane >> 3, us = lane & 7;
        stg_src = Kb + (size_t)(w * 8 + rl) * DHDIM + (us ^ rl) * 8;
        kmul = DHDIM;  // advance by rows: kbase*64 elems
        stg_base = &Ks[0][0] + w * 512;
    } else {      // V^T rows dh=(w-4)*16+dl; unit u holds global ksub u^(dl&3)
        int dl = lane >> 2, ks = lane & 3;
        stg_src = VtB + (size_t)((w - 4) * 16 + dl) * SDIM + (ks ^ (dl & 3)) * 8;
        kmul = 1;      // advance by columns: kbase elems
        stg_base = &Vs[0][0] + (w - 4) * 512;
    }

    float mrow = -3.0e38f, lrow = 0.f;
    f32x4 accO[4] = {};

    // ---- prologue: stage chunk 0 into buf 0; load bias chunk 0 into regs ----
    glds16(stg_src, stg_base);
    bf16x4 bv0 = *(const bf16x4*)(Bq + quad * 4);
    bf16x4 bv1 = *(const bf16x4*)(Bq + 16 + quad * 4);

    for (int c = 0; c < SDIM / 32; c++) {
        __syncthreads();  // compiler drains vmcnt before barrier -> buf[c&1] ready
        const int kbase = c * 32;

        // ---- stage chunk c+1 into other buffer; prefetch bias c+1 ----
        bf16x4 nb0 = bv0, nb1 = bv1;
        if (c < SDIM / 32 - 1) {
            glds16(stg_src + (size_t)(kbase + 32) * kmul, stg_base + ((c + 1) & 1) * 2048);
            nb0 = *(const bf16x4*)(Bq + kbase + 32 + quad * 4);
            nb1 = *(const bf16x4*)(Bq + kbase + 48 + quad * 4);
        }

        // ---- K fragments from LDS (swizzle-corrected) ----
        const bf16_t* Kl = &Ks[c & 1][0];
        const int sw7 = low & 7;
        bf16x8 kA0 = *(const bf16x8*)(Kl + low * 64 + (quad ^ sw7) * 8);
        bf16x8 kA1 = *(const bf16x8*)(Kl + low * 64 + ((quad + 4) ^ sw7) * 8);
        bf16x8 kB0 = *(const bf16x8*)(Kl + (16 + low) * 64 + (quad ^ sw7) * 8);
        bf16x8 kB1 = *(const bf16x8*)(Kl + (16 + low) * 64 + ((quad + 4) ^ sw7) * 8);

        // ---- V fragments from LDS ----
        const bf16_t* Vl = &Vs[c & 1][0];
        const int sw3 = low & 3;
        bf16x8 vf[4];
#pragma unroll
        for (int nt = 0; nt < 4; nt++)
            vf[nt] = *(const bf16x8*)(Vl + (nt * 16 + low) * 32 + (quad ^ sw3) * 8);

        // ---- S^T = K Q^T (row=k, col=q) ----
        f32x4 s0 = {}, s1 = {};
        s0 = __builtin_amdgcn_mfma_f32_16x16x32_bf16(kA0, qf0, s0, 0, 0, 0);
        s0 = __builtin_amdgcn_mfma_f32_16x16x32_bf16(kA1, qf1, s0, 0, 0, 0);
        s1 = __builtin_amdgcn_mfma_f32_16x16x32_bf16(kB0, qf0, s1, 0, 0, 0);
        s1 = __builtin_amdgcn_mfma_f32_16x16x32_bf16(kB1, qf1, s1, 0, 0, 0);

        // ---- + bias (mask folded): lane q = low, k = nt*16 + quad*4 + r ----
        float sv[8];
#pragma unroll
        for (int r = 0; r < 4; r++) {
            sv[r] = s0[r] + (float)bv0[r];
            sv[4 + r] = s1[r] + (float)bv1[r];
        }

        // ---- online softmax, balanced trees; T13 defer-max ----
        float vmx = fmaxf(fmaxf(fmaxf(sv[0], sv[1]), fmaxf(sv[2], sv[3])),
                          fmaxf(fmaxf(sv[4], sv[5]), fmaxf(sv[6], sv[7])));
        vmx = fmaxf(vmx, __shfl_xor(vmx, 16));
        vmx = fmaxf(vmx, __shfl_xor(vmx, 32));
        if (__any(vmx > mrow + 8.f)) {
            float mn = fmaxf(mrow, vmx);
            float alpha = __expf(mrow - mn);
            mrow = mn;
            lrow *= alpha;
#pragma unroll
            for (int r = 0; r < 4; r++) {
                float ar = __shfl(alpha, (lane & 48) | (quad * 4 + r));
#pragma unroll
                for (int nt = 0; nt < 4; nt++) accO[nt][r] *= ar;
            }
        }
        float e[8];
#pragma unroll
        for (int j = 0; j < 8; j++) e[j] = __expf(sv[j] - mrow);
        bf16x4 p0, p1;
#pragma unroll
        for (int j = 0; j < 4; j++) { p0[j] = (bf16_t)e[j]; p1[j] = (bf16_t)e[4 + j]; }
        float ps = ((e[0] + e[1]) + (e[2] + e[3])) + ((e[4] + e[5]) + (e[6] + e[7]));
        ps += __shfl_xor(ps, 16);
        ps += __shfl_xor(ps, 32);
        lrow += ps;

        // ---- P -> wave-private LDS (A layout rows q=low), no barrier ----
        *(bf16x4*)(Pw + low * 40 + quad * 4) = p0;
        *(bf16x4*)(Pw + low * 40 + 16 + quad * 4) = p1;
        bf16x8 pf = *(const bf16x8*)(Pw + low * 40 + quad * 8);

        // ---- O += P V ----
#pragma unroll
        for (int nt = 0; nt < 4; nt++)
            accO[nt] = __builtin_amdgcn_mfma_f32_16x16x32_bf16(pf, vf[nt], accO[nt], 0, 0, 0);

        bv0 = nb0; bv1 = nb1;
    }

    // ---- epilogue: hidden[b, q, h*64+dh] bf16 ----
    float linv = 1.f / lrow;
#pragma unroll
    for (int r = 0; r < 4; r++) {
        float lr = __shfl(linv, (lane & 48) | (quad * 4 + r));
#pragma unroll
        for (int nt = 0; nt < 4; nt++) {
            hid[((size_t)b * SDIM + qw + quad * 4 + r) * DDIM + h * 64 + nt * 16 + low] =
                (bf16_t)(accO[nt][r] * lr);
        }
    }
}

// ---------------- launcher ----------------

extern "C" void kernel_launch(void* const* d_in, const int* in_sizes, int n_in,
                              void* d_out, int out_size, void* d_ws, size_t ws_size,
                              hipStream_t stream) {
    const float* X = (const float*)d_in[0];
    const unsigned char* maskb = (const unsigned char*)d_in[1];
    const float* inter = (const float*)d_in[2];
    const float* WQ = (const float*)d_in[3];
    const float* WK = (const float*)d_in[4];
    const float* WV = (const float*)d_in[5];
    const float* WO = (const float*)d_in[6];
    float* out = (float*)d_out;

    char* ws = (char*)d_ws;
    const size_t MB = 1024 * 1024;
    bf16_t* Xb    = (bf16_t*)(ws + 0 * MB);
    bf16_t* Wt    = (bf16_t*)(ws + 8 * MB);    // [4][1024][1024] bf16 transposed
    bf16_t* Qm    = (bf16_t*)(ws + 16 * MB);   // [B,H,S,DH]
    bf16_t* Km    = (bf16_t*)(ws + 24 * MB);   // [B,H,S,DH]
    bf16_t* Vtm   = (bf16_t*)(ws + 32 * MB);   // [B,H,DH,S]  (transposed V)
    bf16_t* hid   = (bf16_t*)(ws + 40 * MB);   // [B,S,D] bf16
    int* flag     = (int*)(ws + 48 * MB);
    bf16_t* biasT = (bf16_t*)(ws + 64 * MB);   // [B,H,S,S] bf16, mask folded (134 MB)

    convert_x_kernel<<<BDIM * SDIM * DDIM / (256 * 4), 256, 0, stream>>>(X, Xb, BDIM * SDIM * DDIM);
    transpose_w_kernel<<<dim3(32, 32, 4), 256, 0, stream>>>(WQ, WK, WV, WO, Wt);
    mask_flag_kernel<<<1, 1024, 0, stream>>>(maskb, flag);
    transpose_bias_kernel<<<dim3(8, 128, 4), 256, 0, stream>>>(inter, maskb, flag, biasT);
    gemm_bt_kernel<0><<<dim3(32, 24), 256, 0, stream>>>(Xb, Wt, Qm, Km, Vtm, nullptr);
    attn_kernel<<<dim3(512), 512, 0, stream>>>(Qm, Km, Vtm, biasT, hid);
    gemm_bt_kernel<1><<<dim3(32, 8), 256, 0, stream>>>(hid, Wt + (size_t)3 * DDIM * DDIM,
                                                       nullptr, nullptr, nullptr, out);
}